// Round 7
// baseline (116.190 us; speedup 1.0000x reference)
//
#include <hip/hip_runtime.h>
#include <hip/hip_fp16.h>

constexpr int B_  = 8;
constexpr int LQ  = 8192;
constexpr int LK  = 1024;
constexpr int NF  = 64;

typedef _Float16 f16x8  __attribute__((ext_vector_type(8)));
typedef float    f32x16 __attribute__((ext_vector_type(16)));

#define MFMA32(a, b, c) __builtin_amdgcn_mfma_f32_32x32x16_f16((a), (b), (c), 0, 0, 0)

__device__ __forceinline__ f16x8 ldf(const _Float16* p) { return *(const f16x8*)p; }

// fp32 row -> A/B frag for kstep t, lane-half h. Covers logical d/k indices
// 32(t>>1)+16(t&1)+4h + {0,1,2,3, 8,9,10,11}  (the baked permutation).
__device__ __forceinline__ f16x8 ldfrag_f32(const float* row, int t, int h) {
  int off = 32 * (t >> 1) + 16 * (t & 1) + 4 * h;
  float4 r0 = *(const float4*)(row + off);
  float4 r1 = *(const float4*)(row + off + 8);
  f16x8 r;
  r[0] = (_Float16)r0.x; r[1] = (_Float16)r0.y; r[2] = (_Float16)r0.z; r[3] = (_Float16)r0.w;
  r[4] = (_Float16)r1.x; r[5] = (_Float16)r1.y; r[6] = (_Float16)r1.z; r[7] = (_Float16)r1.w;
  return r;
}

// 32x32 C-regs half u (regs 8u..8u+7) -> one A/B frag (kstep t = 2*blk + u).
// Valid because position p=16t+8h+j is baked to hold logical index
// 16u + 4h + 8*(j>>2) + (j&3) == C-row of reg r=8u+j. Pure in-lane.
__device__ __forceinline__ f16x8 pk8(const f32x16 c, int u) {
  int b = u * 8;
  auto p0 = __builtin_amdgcn_cvt_pkrtz(c[b],     c[b + 1]);
  auto p1 = __builtin_amdgcn_cvt_pkrtz(c[b + 2], c[b + 3]);
  auto p2 = __builtin_amdgcn_cvt_pkrtz(c[b + 4], c[b + 5]);
  auto p3 = __builtin_amdgcn_cvt_pkrtz(c[b + 6], c[b + 7]);
  f16x8 r;
  r[0] = p0[0]; r[1] = p0[1]; r[2] = p1[0]; r[3] = p1[1];
  r[4] = p2[0]; r[5] = p2[1]; r[6] = p3[0]; r[7] = p3[1];
  return r;
}

// Weight-staging index map: element idx in [0,4096) of a frag-linear 8-chunk
// weight block -> source index into a 64x64 row-major W (value W[din][dout]).
__device__ __forceinline__ int w_src_idx(int idx) {
  int chunk = idx >> 9, r9 = idx & 511;
  int lane_ = r9 >> 3, j = r9 & 7;
  int m32 = lane_ & 31, h = lane_ >> 5;
  int tt = chunk & 3;
  int din  = 32 * (tt >> 1) + 16 * (tt & 1) + 4 * h + 8 * (j >> 2) + (j & 3);
  int dout = (chunk >> 2) * 32 + m32;
  return din * 64 + dout;
}

// Async global->LDS DMA, 16 B/lane; LDS dst = wave-uniform base + lane*16.
__device__ __forceinline__ void dma16(const _Float16* g, _Float16* l) {
  __builtin_amdgcn_global_load_lds(
      (const __attribute__((address_space(1))) unsigned int*)g,
      (__attribute__((address_space(3))) unsigned int*)l, 16, 0, 0);
}

// Barrier without draining the prefetch: at call site the only outstanding
// vmem is the CURRENT tile's DMA; next tile's DMA is issued after.
__device__ __forceinline__ void tile_barrier() {
  asm volatile("s_waitcnt vmcnt(0)\n\ts_barrier" ::: "memory");
}

// ---------------------------------------------------------------------------
// Kernel A: K/V projection -> frag-linear 64-key tiles for 32x32x16 consumers.
// Tile T = b*16 + kt (8192 f16): K chunks [kb*4+t] (A-frag: K[key][d-pos]),
// then V chunks 4096 + [nb*4+t'] (B-frag: V[key-pos][dout]).
// grid = B*(LK/128) = 64 blocks x 256 (wave -> 32 keys; 2 tiles per block).
// ---------------------------------------------------------------------------
__global__ __launch_bounds__(256) void kv_proj_kernel(
    const float* __restrict__ kv, const float* __restrict__ Wk,
    const float* __restrict__ Wv, _Float16* __restrict__ KV) {
  __shared__ __align__(16) _Float16 wlds[8192];   // [Wk A-frags | Wv B-frags]

  const int t    = threadIdx.x;
  const int wave = t >> 6, lane = t & 63, m32 = lane & 31, h = lane >> 5;
  const int bb   = blockIdx.x >> 3;      // batch
  const int kblk = blockIdx.x & 7;       // 128-key block

#pragma unroll
  for (int i = 0; i < 16; ++i) {
    int idx = t + 256 * i;
    int s = w_src_idx(idx);
    wlds[idx]        = (_Float16)Wk[s];
    wlds[4096 + idx] = (_Float16)Wv[s];
  }

  const int key = kblk * 128 + wave * 32 + m32;
  const float* kvrow = kv + ((size_t)bb * LK + key) * NF;
  f16x8 kvf[4];
#pragma unroll
  for (int tt = 0; tt < 4; ++tt) kvf[tt] = ldfrag_f32(kvrow, tt, h);
  __syncthreads();

  const int T = bb * 16 + kblk * 2 + (wave >> 1);
  _Float16* tile = KV + (size_t)T * 8192;
  const int kb = wave & 1;   // 32-key block within the 64-key tile

  // K^T = Wk^T · kv^T : C col = key (=m32), rows = dout
#pragma unroll
  for (int mb = 0; mb < 2; ++mb) {
    f32x16 C = {};
#pragma unroll
    for (int tt = 0; tt < 4; ++tt)
      C = MFMA32(ldf(&wlds[(mb * 4 + tt) * 512 + lane * 8]), kvf[tt], C);
#pragma unroll
    for (int u = 0; u < 2; ++u)
      *(f16x8*)(tile + ((size_t)(kb * 4 + 2 * mb + u)) * 512 + lane * 8) = pk8(C, u);
  }
  // V = kv · Wv : C col = dout (=m32), rows = key-local
#pragma unroll
  for (int nb = 0; nb < 2; ++nb) {
    f32x16 C = {};
#pragma unroll
    for (int tt = 0; tt < 4; ++tt)
      C = MFMA32(kvf[tt], ldf(&wlds[4096 + (nb * 4 + tt) * 512 + lane * 8]), C);
#pragma unroll
    for (int u = 0; u < 2; ++u)
      *(f16x8*)(tile + 4096 + ((size_t)(nb * 4 + 2 * kb + u)) * 512 + lane * 8) = pk8(C, u);
  }
}

// ---------------------------------------------------------------------------
// Kernel B: fused Q-proj + flash attention, 32x32x16 MFMA, 64 q/wave.
// grid = B*(LQ/256) = 256 blocks x 256 thr (4 waves x 64 q). 64-key tiles,
// double-buffered DMA, async tile barrier, l = P·1 via MFMA (rows match oacc).
// ---------------------------------------------------------------------------
__global__ __launch_bounds__(256, 1) void attn_kernel(
    const float* __restrict__ x, const float* __restrict__ Wq,
    const _Float16* __restrict__ KV, float* __restrict__ out) {
  __shared__ __align__(16) _Float16 lds[2 * 8192 + 4096];  // 2 tile bufs + WqT

  const int t    = threadIdx.x;
  const int wave = t >> 6, lane = t & 63, m32 = lane & 31, h = lane >> 5;
  const int b    = blockIdx.x >> 5;
  const int qw_base = (blockIdx.x & 31) * 256 + wave * 64;
  constexpr float LOG2E = 1.44269504088896f;

  _Float16* wq_l = lds + 16384;
#pragma unroll
  for (int i = 0; i < 16; ++i) {
    int idx = t + 256 * i;
    wq_l[idx] = (_Float16)(Wq[w_src_idx(idx)] * LOG2E);
  }

  const _Float16* KVb = KV + (size_t)b * 16 * 8192;
  // DMA tile 0 -> buf 0 (wave w: chunks 4w..4w+3 of 16)
#pragma unroll
  for (int q = 0; q < 4; ++q) {
    int ch = wave * 4 + q;
    dma16(KVb + ch * 512 + lane * 8, lds + ch * 512);
  }
  __syncthreads();  // wq + tile0 ready

  // ---- Q^T = Wq^T · x^T; C-regs -> B-frags in-lane ----
  f16x8 qb[2][4];
  {
    f16x8 wa[2][4];
#pragma unroll
    for (int mb = 0; mb < 2; ++mb)
#pragma unroll
      for (int tt = 0; tt < 4; ++tt)
        wa[mb][tt] = ldf(&wq_l[(mb * 4 + tt) * 512 + lane * 8]);
#pragma unroll
    for (int s = 0; s < 2; ++s) {
      const float* xrow = x + ((size_t)b * LQ + qw_base + s * 32 + m32) * NF;
      f16x8 xf[4];
#pragma unroll
      for (int tt = 0; tt < 4; ++tt) xf[tt] = ldfrag_f32(xrow, tt, h);
#pragma unroll
      for (int mb = 0; mb < 2; ++mb) {
        f32x16 C = {};
#pragma unroll
        for (int tt = 0; tt < 4; ++tt) C = MFMA32(wa[mb][tt], xf[tt], C);
        qb[s][2 * mb]     = pk8(C, 0);
        qb[s][2 * mb + 1] = pk8(C, 1);
      }
    }
  }

  f16x8 ones;
#pragma unroll
  for (int j = 0; j < 8; ++j) ones[j] = (_Float16)1.0f;

  float  m_s[2] = {-1e30f, -1e30f};
  f32x16 lacc[2] = {};
  f32x16 oacc[2][2] = {};

  for (int tile = 0; tile < 16; ++tile) {
    tile_barrier();               // waits only THIS tile's DMA; syncs waves
    if (tile < 15) {
      const _Float16* nt = KVb + (size_t)(tile + 1) * 8192;
      _Float16* nb_ = lds + ((tile + 1) & 1) * 8192;
#pragma unroll
      for (int q = 0; q < 4; ++q) {
        int ch = wave * 4 + q;
        dma16(nt + ch * 512 + lane * 8, nb_ + ch * 512);
      }
    }
    const _Float16* tb = lds + (tile & 1) * 8192;

    // ---- S^T = K·Q^T: C col = q (=m32), rows = key-local per kb ----
    f32x16 st[2][2] = {};
#pragma unroll
    for (int kb = 0; kb < 2; ++kb)
#pragma unroll
      for (int tt = 0; tt < 4; ++tt) {
        f16x8 a = ldf(tb + (size_t)(kb * 4 + tt) * 512 + lane * 8);
        st[0][kb] = MFMA32(a, qb[0][tt], st[0][kb]);
        st[1][kb] = MFMA32(a, qb[1][tt], st[1][kb]);
      }

    // ---- online softmax (query = s*32 + m32; one shuffle only) ----
    f16x8 pa[2][4];
#pragma unroll
    for (int s = 0; s < 2; ++s) {
      float tmax = st[s][0][0];
#pragma unroll
      for (int kb = 0; kb < 2; ++kb)
#pragma unroll
        for (int r = 1 - kb; r < 16; ++r) tmax = fmaxf(tmax, st[s][kb][r]);
      tmax = fmaxf(tmax, __shfl_xor(tmax, 32));

      if (__ballot(tmax > m_s[s]) != 0) {
        float mnew  = fmaxf(m_s[s], tmax);
        float alpha = __builtin_amdgcn_exp2f(m_s[s] - mnew);
        m_s[s] = mnew;
        float ar[16];
#pragma unroll
        for (int r = 0; r < 16; ++r)
          ar[r] = __shfl(alpha, (r & 3) + 8 * (r >> 2) + 4 * h);
#pragma unroll
        for (int r = 0; r < 16; ++r) {
          lacc[s][r]    *= ar[r];
          oacc[s][0][r] *= ar[r];
          oacc[s][1][r] *= ar[r];
        }
      }

#pragma unroll
      for (int kb = 0; kb < 2; ++kb)
#pragma unroll
        for (int r = 0; r < 16; ++r)
          st[s][kb][r] = __builtin_amdgcn_exp2f(st[s][kb][r] - m_s[s]);

#pragma unroll
      for (int kb = 0; kb < 2; ++kb) {
        pa[s][2 * kb]     = pk8(st[s][kb], 0);
        pa[s][2 * kb + 1] = pk8(st[s][kb], 1);
      }
      // l += P·1 : C rows = q-local, exactly oacc's row indexing
#pragma unroll
      for (int tt = 0; tt < 4; ++tt) lacc[s] = MFMA32(pa[s][tt], ones, lacc[s]);
    }

    // ---- O += P·V ----
#pragma unroll
    for (int nb = 0; nb < 2; ++nb)
#pragma unroll
      for (int tt = 0; tt < 4; ++tt) {
        f16x8 vb = ldf(tb + 4096 + (size_t)(nb * 4 + tt) * 512 + lane * 8);
        oacc[0][nb] = MFMA32(pa[0][tt], vb, oacc[0][nb]);
        oacc[1][nb] = MFMA32(pa[1][tt], vb, oacc[1][nb]);
      }
  }

  // ---- epilogue: rows = q-local for both oacc and lacc ----
#pragma unroll
  for (int s = 0; s < 2; ++s)
#pragma unroll
    for (int r = 0; r < 16; ++r) {
      float linv = 1.0f / lacc[s][r];
      int q_out = qw_base + s * 32 + (r & 3) + 8 * (r >> 2) + 4 * h;
      float* orow = out + ((size_t)b * LQ + q_out) * NF + m32;
      orow[0]  = oacc[s][0][r] * linv;
      orow[32] = oacc[s][1][r] * linv;
    }
}

extern "C" void kernel_launch(void* const* d_in, const int* in_sizes, int n_in,
                              void* d_out, int out_size, void* d_ws, size_t ws_size,
                              hipStream_t stream) {
  const float* x  = (const float*)d_in[0];
  const float* kv = (const float*)d_in[1];
  const float* Wq = (const float*)d_in[2];
  const float* Wk = (const float*)d_in[3];
  const float* Wv = (const float*)d_in[4];
  float* out = (float*)d_out;

  _Float16* KV = (_Float16*)d_ws;   // [B][16 tiles][K 4096 | V 4096] f16 = 2 MB

  kv_proj_kernel<<<B_ * (LK / 128), 256, 0, stream>>>(kv, Wk, Wv, KV);
  attn_kernel<<<B_ * (LQ / 256), 256, 0, stream>>>(x, Wq, KV, out);
}

// Round 8
// 111.940 us; speedup vs baseline: 1.0380x; 1.0380x over previous
//
#include <hip/hip_runtime.h>
#include <hip/hip_fp16.h>

constexpr int B_  = 8;
constexpr int LQ  = 8192;
constexpr int LK  = 1024;
constexpr int NF  = 64;

typedef _Float16 f16x8  __attribute__((ext_vector_type(8)));
typedef float    f32x16 __attribute__((ext_vector_type(16)));

#define MFMA32(a, b, c) __builtin_amdgcn_mfma_f32_32x32x16_f16((a), (b), (c), 0, 0, 0)

__device__ __forceinline__ f16x8 ldf(const _Float16* p) { return *(const f16x8*)p; }

// fp32 row -> A/B frag for kstep t, lane-half h (baked permutation).
__device__ __forceinline__ f16x8 ldfrag_f32(const float* row, int t, int h) {
  int off = 32 * (t >> 1) + 16 * (t & 1) + 4 * h;
  float4 r0 = *(const float4*)(row + off);
  float4 r1 = *(const float4*)(row + off + 8);
  f16x8 r;
  r[0] = (_Float16)r0.x; r[1] = (_Float16)r0.y; r[2] = (_Float16)r0.z; r[3] = (_Float16)r0.w;
  r[4] = (_Float16)r1.x; r[5] = (_Float16)r1.y; r[6] = (_Float16)r1.z; r[7] = (_Float16)r1.w;
  return r;
}

// 32x32 C-regs half u (regs 8u..8u+7) -> one A/B frag (kstep t = 2*blk + u).
__device__ __forceinline__ f16x8 pk8(const f32x16 c, int u) {
  int b = u * 8;
  auto p0 = __builtin_amdgcn_cvt_pkrtz(c[b],     c[b + 1]);
  auto p1 = __builtin_amdgcn_cvt_pkrtz(c[b + 2], c[b + 3]);
  auto p2 = __builtin_amdgcn_cvt_pkrtz(c[b + 4], c[b + 5]);
  auto p3 = __builtin_amdgcn_cvt_pkrtz(c[b + 6], c[b + 7]);
  f16x8 r;
  r[0] = p0[0]; r[1] = p0[1]; r[2] = p1[0]; r[3] = p1[1];
  r[4] = p2[0]; r[5] = p2[1]; r[6] = p3[0]; r[7] = p3[1];
  return r;
}

// frag-linear weight-block element -> source index in 64x64 row-major W.
__device__ __forceinline__ int w_src_idx(int idx) {
  int chunk = idx >> 9, r9 = idx & 511;
  int lane_ = r9 >> 3, j = r9 & 7;
  int m32 = lane_ & 31, h = lane_ >> 5;
  int tt = chunk & 3;
  int din  = 32 * (tt >> 1) + 16 * (tt & 1) + 4 * h + 8 * (j >> 2) + (j & 3);
  int dout = (chunk >> 2) * 32 + m32;
  return din * 64 + dout;
}

__device__ __forceinline__ void dma16(const _Float16* g, _Float16* l) {
  __builtin_amdgcn_global_load_lds(
      (const __attribute__((address_space(1))) unsigned int*)g,
      (__attribute__((address_space(3))) unsigned int*)l, 16, 0, 0);
}

// Barrier without draining the prefetch (only the CURRENT tile's DMA is
// outstanding at the call site; the next tile's DMA is issued after).
__device__ __forceinline__ void tile_barrier() {
  asm volatile("s_waitcnt vmcnt(0)\n\ts_barrier" ::: "memory");
}

// ---------------------------------------------------------------------------
// Kernel A (unchanged from R7): frag-linear 64-key tiles for 32x32x16.
// grid = B*(LK/128) = 64 blocks x 256.
// ---------------------------------------------------------------------------
__global__ __launch_bounds__(256) void kv_proj_kernel(
    const float* __restrict__ kv, const float* __restrict__ Wk,
    const float* __restrict__ Wv, _Float16* __restrict__ KV) {
  __shared__ __align__(16) _Float16 wlds[8192];

  const int t    = threadIdx.x;
  const int wave = t >> 6, lane = t & 63, m32 = lane & 31, h = lane >> 5;
  const int bb   = blockIdx.x >> 3;
  const int kblk = blockIdx.x & 7;

#pragma unroll
  for (int i = 0; i < 16; ++i) {
    int idx = t + 256 * i;
    int s = w_src_idx(idx);
    wlds[idx]        = (_Float16)Wk[s];
    wlds[4096 + idx] = (_Float16)Wv[s];
  }

  const int key = kblk * 128 + wave * 32 + m32;
  const float* kvrow = kv + ((size_t)bb * LK + key) * NF;
  f16x8 kvf[4];
#pragma unroll
  for (int tt = 0; tt < 4; ++tt) kvf[tt] = ldfrag_f32(kvrow, tt, h);
  __syncthreads();

  const int T = bb * 16 + kblk * 2 + (wave >> 1);
  _Float16* tile = KV + (size_t)T * 8192;
  const int kb = wave & 1;

#pragma unroll
  for (int mb = 0; mb < 2; ++mb) {
    f32x16 C = {};
#pragma unroll
    for (int tt = 0; tt < 4; ++tt)
      C = MFMA32(ldf(&wlds[(mb * 4 + tt) * 512 + lane * 8]), kvf[tt], C);
#pragma unroll
    for (int u = 0; u < 2; ++u)
      *(f16x8*)(tile + ((size_t)(kb * 4 + 2 * mb + u)) * 512 + lane * 8) = pk8(C, u);
  }
#pragma unroll
  for (int nb = 0; nb < 2; ++nb) {
    f32x16 C = {};
#pragma unroll
    for (int tt = 0; tt < 4; ++tt)
      C = MFMA32(kvf[tt], ldf(&wlds[4096 + (nb * 4 + tt) * 512 + lane * 8]), C);
#pragma unroll
    for (int u = 0; u < 2; ++u)
      *(f16x8*)(tile + 4096 + ((size_t)(nb * 4 + 2 * kb + u)) * 512 + lane * 8) = pk8(C, u);
  }
}

// ---------------------------------------------------------------------------
// Kernel B: fused Q-proj + flash attention, 32x32x16, 64 q/wave, IN-BLOCK
// KEY SPLIT. 512 thr = 8 waves: wq_i = wave&3 (64-q subgroup), wg = wave>>2
// (key half: tiles wg*8 .. wg*8+7). Partials merged through LDS at the end.
// grid = B*(LQ/256) = 256 blocks -> 8 waves/CU (2/SIMD).
// ---------------------------------------------------------------------------
__global__ __launch_bounds__(512, 2) void attn_kernel(
    const float* __restrict__ x, const float* __restrict__ Wq,
    const _Float16* __restrict__ KV, float* __restrict__ out) {
  __shared__ __align__(16) _Float16 lds[2][2][8192];   // [key-group][buf][tile] 64 KB
  __shared__ __align__(16) _Float16 wq_l[4096];        // Wq^T frag-linear, 8 KB

  const int t    = threadIdx.x;
  const int wave = t >> 6, lane = t & 63, m32 = lane & 31, h = lane >> 5;
  const int wq_i = wave & 3, wg = wave >> 2;
  const int b    = blockIdx.x >> 5;
  const int qw_base = (blockIdx.x & 31) * 256 + wq_i * 64;
  constexpr float LOG2E = 1.44269504088896f;

#pragma unroll
  for (int i = 0; i < 8; ++i) {
    int idx = t + 512 * i;
    wq_l[idx] = (_Float16)(Wq[w_src_idx(idx)] * LOG2E);
  }

  const _Float16* Kg = KV + ((size_t)b * 16 + wg * 8) * 8192;  // this group's 8 tiles
  // DMA group-tile 0 -> buf 0 (each wave: 4 of the group's 16 chunks)
#pragma unroll
  for (int q = 0; q < 4; ++q) {
    int ch = wq_i * 4 + q;
    dma16(Kg + ch * 512 + lane * 8, &lds[wg][0][ch * 512]);
  }
  __syncthreads();  // wq_l + tile0 ready

  // ---- Q^T = Wq^T · x^T; C-regs -> B-frags in-lane ----
  f16x8 qb[2][4];
  {
    f16x8 wa[2][4];
#pragma unroll
    for (int mb = 0; mb < 2; ++mb)
#pragma unroll
      for (int tt = 0; tt < 4; ++tt)
        wa[mb][tt] = ldf(&wq_l[(mb * 4 + tt) * 512 + lane * 8]);
#pragma unroll
    for (int s = 0; s < 2; ++s) {
      const float* xrow = x + ((size_t)b * LQ + qw_base + s * 32 + m32) * NF;
      f16x8 xf[4];
#pragma unroll
      for (int tt = 0; tt < 4; ++tt) xf[tt] = ldfrag_f32(xrow, tt, h);
#pragma unroll
      for (int mb = 0; mb < 2; ++mb) {
        f32x16 C = {};
#pragma unroll
        for (int tt = 0; tt < 4; ++tt) C = MFMA32(wa[mb][tt], xf[tt], C);
        qb[s][2 * mb]     = pk8(C, 0);
        qb[s][2 * mb + 1] = pk8(C, 1);
      }
    }
  }

  f16x8 ones;
#pragma unroll
  for (int j = 0; j < 8; ++j) ones[j] = (_Float16)1.0f;

  float  m_s[2] = {-1e30f, -1e30f};
  f32x16 lacc[2] = {};
  f32x16 oacc[2][2] = {};

  for (int tile = 0; tile < 8; ++tile) {
    tile_barrier();               // waits only THIS tile's DMA; syncs 8 waves
    if (tile < 7) {
      const _Float16* nt = Kg + (size_t)(tile + 1) * 8192;
      _Float16* nb_ = &lds[wg][(tile + 1) & 1][0];
#pragma unroll
      for (int q = 0; q < 4; ++q) {
        int ch = wq_i * 4 + q;
        dma16(nt + ch * 512 + lane * 8, nb_ + ch * 512);
      }
    }
    const _Float16* tb = &lds[wg][tile & 1][0];

    // ---- S^T = K·Q^T: C col = q (=m32), rows = key-local ----
    f32x16 st[2][2] = {};
#pragma unroll
    for (int kb = 0; kb < 2; ++kb)
#pragma unroll
      for (int tt = 0; tt < 4; ++tt) {
        f16x8 a = ldf(tb + (size_t)(kb * 4 + tt) * 512 + lane * 8);
        st[0][kb] = MFMA32(a, qb[0][tt], st[0][kb]);
        st[1][kb] = MFMA32(a, qb[1][tt], st[1][kb]);
      }

    // ---- online softmax (query = s*32 + m32; one shuffle) ----
    f16x8 pa[2][4];
#pragma unroll
    for (int s = 0; s < 2; ++s) {
      float tmax = st[s][0][0];
#pragma unroll
      for (int kb = 0; kb < 2; ++kb)
#pragma unroll
        for (int r = 1 - kb; r < 16; ++r) tmax = fmaxf(tmax, st[s][kb][r]);
      tmax = fmaxf(tmax, __shfl_xor(tmax, 32));

      if (__ballot(tmax > m_s[s]) != 0) {
        float mnew  = fmaxf(m_s[s], tmax);
        float alpha = __builtin_amdgcn_exp2f(m_s[s] - mnew);
        m_s[s] = mnew;
        float ar[16];
#pragma unroll
        for (int r = 0; r < 16; ++r)
          ar[r] = __shfl(alpha, (r & 3) + 8 * (r >> 2) + 4 * h);
#pragma unroll
        for (int r = 0; r < 16; ++r) {
          lacc[s][r]    *= ar[r];
          oacc[s][0][r] *= ar[r];
          oacc[s][1][r] *= ar[r];
        }
      }

#pragma unroll
      for (int kb = 0; kb < 2; ++kb)
#pragma unroll
        for (int r = 0; r < 16; ++r)
          st[s][kb][r] = __builtin_amdgcn_exp2f(st[s][kb][r] - m_s[s]);

#pragma unroll
      for (int kb = 0; kb < 2; ++kb) {
        pa[s][2 * kb]     = pk8(st[s][kb], 0);
        pa[s][2 * kb + 1] = pk8(st[s][kb], 1);
      }
#pragma unroll
      for (int tt = 0; tt < 4; ++tt) lacc[s] = MFMA32(pa[s][tt], ones, lacc[s]);
    }

    // ---- O += P·V ----
#pragma unroll
    for (int nb = 0; nb < 2; ++nb)
#pragma unroll
      for (int tt = 0; tt < 4; ++tt) {
        f16x8 vb = ldf(tb + 4096 + (size_t)(nb * 4 + tt) * 512 + lane * 8);
        oacc[0][nb] = MFMA32(pa[0][tt], vb, oacc[0][nb]);
        oacc[1][nb] = MFMA32(pa[1][tt], vb, oacc[1][nb]);
      }
  }

  // ---- in-block merge of the two key-halves (2 phases, LDS reuse) ----
  float* mrg_m = (float*)&lds[0][0][0];   // [4][64]
  float* mrg_l = mrg_m + 256;             // [4][16][64]
  float* mrg_o = mrg_l + 4096;            // [4][32][64]   total 50 KB <= 64 KB

#pragma unroll
  for (int s = 0; s < 2; ++s) {
    __syncthreads();                      // tiles (or prev phase) no longer needed
    if (wg == 1) {
      mrg_m[wq_i * 64 + lane] = m_s[s];
#pragma unroll
      for (int r = 0; r < 16; ++r)
        mrg_l[(wq_i * 16 + r) * 64 + lane] = lacc[s][r];
#pragma unroll
      for (int nb = 0; nb < 2; ++nb)
#pragma unroll
        for (int r = 0; r < 16; ++r)
          mrg_o[(wq_i * 32 + nb * 16 + r) * 64 + lane] = oacc[s][nb][r];
    }
    __syncthreads();
    if (wg == 0) {
      float mh = mrg_m[wq_i * 64 + lane];
      float mx = fmaxf(m_s[s], mh);
      float al = __builtin_amdgcn_exp2f(m_s[s] - mx);
      float ah = __builtin_amdgcn_exp2f(mh - mx);
      float alr[16], ahr[16];
#pragma unroll
      for (int r = 0; r < 16; ++r) {
        int src = (r & 3) + 8 * (r >> 2) + 4 * h;
        alr[r] = __shfl(al, src);
        ahr[r] = __shfl(ah, src);
      }
#pragma unroll
      for (int r = 0; r < 16; ++r) {
        float lh = mrg_l[(wq_i * 16 + r) * 64 + lane];
        float linv = 1.0f / (alr[r] * lacc[s][r] + ahr[r] * lh);
        int q_out = qw_base + s * 32 + (r & 3) + 8 * (r >> 2) + 4 * h;
        float* orow = out + ((size_t)b * LQ + q_out) * NF + m32;
        float o0 = alr[r] * oacc[s][0][r] + ahr[r] * mrg_o[(wq_i * 32 + r) * 64 + lane];
        float o1 = alr[r] * oacc[s][1][r] + ahr[r] * mrg_o[(wq_i * 32 + 16 + r) * 64 + lane];
        orow[0]  = o0 * linv;
        orow[32] = o1 * linv;
      }
    }
  }
}

extern "C" void kernel_launch(void* const* d_in, const int* in_sizes, int n_in,
                              void* d_out, int out_size, void* d_ws, size_t ws_size,
                              hipStream_t stream) {
  const float* x  = (const float*)d_in[0];
  const float* kv = (const float*)d_in[1];
  const float* Wq = (const float*)d_in[2];
  const float* Wk = (const float*)d_in[3];
  const float* Wv = (const float*)d_in[4];
  float* out = (float*)d_out;

  _Float16* KV = (_Float16*)d_ws;   // [B][16 tiles][K 4096 | V 4096] f16 = 2 MB

  kv_proj_kernel<<<B_ * (LK / 128), 256, 0, stream>>>(kv, Wk, Wv, KV);
  attn_kernel<<<B_ * (LQ / 256), 512, 0, stream>>>(x, Wq, KV, out);
}